// Round 1
// baseline (89074.536 us; speedup 1.0000x reference)
//
#include <hip/hip_runtime.h>
#include <stdint.h>

// MambaBlock: DIM=1024, BATCH=8, SEQ=4096.
//   inp  = x @ W_in^T + b_in                  (fp32, stored in d_out temporarily)
//   gate = sigmoid(inp @ W_gate^T + b_gate)   (bf16 in ws)
//   u    = inp @ B^T                          (bf16 in ws)
//   scan: s_t = g*tanh(s_{t-1}@A^T + u_t) + (1-g)*inp_t   (fp32, slice-exchange in ws)
//   out  = states @ W_out^T + b_out           (fp32 -> d_out)

#define D 1024
#define NBATCH 8
#define SEQ 4096
#define NROWS 32768  // NBATCH*SEQ

static constexpr size_t FLAGS_BYTES = 16384;                     // 256 flags padded to 64B lines
static constexpr size_t GATE_BYTES  = (size_t)NROWS * D * 2;     // 64 MiB bf16
static constexpr size_t U_BYTES     = (size_t)NROWS * D * 2;     // 64 MiB bf16
// slice buffer: [SEQ][256 wg][8 b][4 j] fp32 = 128 MiB; each (t,g) chunk = 128 B, WG-private lines.

__device__ __forceinline__ float bf2f(uint16_t h) {
  uint32_t u = ((uint32_t)h) << 16;
  return __builtin_bit_cast(float, u);
}
__device__ __forceinline__ uint16_t f2bf(float f) {
  uint32_t u = __builtin_bit_cast(uint32_t, f);
  u = u + 0x7fffu + ((u >> 16) & 1u);   // RNE
  return (uint16_t)(u >> 16);
}

// ---------------- GEMM 1: inp = x @ W_in^T + b_in (fp32 out) ----------------
// 64x64 tile, BK=16, 4x4 microtile. Both operands K-contiguous (NT gemm).
__global__ __launch_bounds__(256) void k_gemm_in(
    const float* __restrict__ X, const float* __restrict__ W,
    const float* __restrict__ bias, float* __restrict__ Y) {
  __shared__ float Xs[16][68];
  __shared__ float Ws[16][68];
  const int tid = threadIdx.x;
  const int m0 = blockIdx.y << 6, n0 = blockIdx.x << 6;
  const int tx = tid & 15, ty = tid >> 4;
  const int lr = tid >> 2, lk = (tid & 3) << 2;
  float acc[4][4] = {};
  const float* xp = X + (size_t)(m0 + lr) * D + lk;
  const float* wp = W + (size_t)(n0 + lr) * D + lk;
  for (int k0 = 0; k0 < D; k0 += 16) {
    float4 xv = *(const float4*)(xp + k0);
    float4 wv = *(const float4*)(wp + k0);
    __syncthreads();
    Xs[lk + 0][lr] = xv.x; Xs[lk + 1][lr] = xv.y; Xs[lk + 2][lr] = xv.z; Xs[lk + 3][lr] = xv.w;
    Ws[lk + 0][lr] = wv.x; Ws[lk + 1][lr] = wv.y; Ws[lk + 2][lr] = wv.z; Ws[lk + 3][lr] = wv.w;
    __syncthreads();
#pragma unroll
    for (int k = 0; k < 16; ++k) {
      float4 av = *(const float4*)&Xs[k][tx << 2];
      float4 bv = *(const float4*)&Ws[k][ty << 2];
      const float aa[4] = {av.x, av.y, av.z, av.w};
      const float bb[4] = {bv.x, bv.y, bv.z, bv.w};
#pragma unroll
      for (int i = 0; i < 4; ++i)
#pragma unroll
        for (int jj = 0; jj < 4; ++jj) acc[i][jj] += aa[i] * bb[jj];
    }
  }
  const int nc = n0 + (ty << 2);
#pragma unroll
  for (int i = 0; i < 4; ++i) {
    const int row = m0 + (tx << 2) + i;
    float4 o;
    o.x = acc[i][0] + bias[nc + 0];
    o.y = acc[i][1] + bias[nc + 1];
    o.z = acc[i][2] + bias[nc + 2];
    o.w = acc[i][3] + bias[nc + 3];
    *(float4*)&Y[(size_t)row * D + nc] = o;
  }
}

// ------- GEMM 2 (fused): gate = sigmoid(inp@Wg^T + bg), u = inp@B^T (bf16 out) -------
__global__ __launch_bounds__(256) void k_gemm_gate_u(
    const float* __restrict__ X, const float* __restrict__ Wg,
    const float* __restrict__ bg, const float* __restrict__ Bu,
    uint16_t* __restrict__ G, uint16_t* __restrict__ U) {
  __shared__ float Xs[16][68];
  __shared__ float Wgs[16][68];
  __shared__ float Wus[16][68];
  const int tid = threadIdx.x;
  const int m0 = blockIdx.y << 6, n0 = blockIdx.x << 6;
  const int tx = tid & 15, ty = tid >> 4;
  const int lr = tid >> 2, lk = (tid & 3) << 2;
  float accg[4][4] = {}, accu[4][4] = {};
  const float* xp = X + (size_t)(m0 + lr) * D + lk;
  const float* wgp = Wg + (size_t)(n0 + lr) * D + lk;
  const float* wup = Bu + (size_t)(n0 + lr) * D + lk;
  for (int k0 = 0; k0 < D; k0 += 16) {
    float4 xv = *(const float4*)(xp + k0);
    float4 gv = *(const float4*)(wgp + k0);
    float4 uv = *(const float4*)(wup + k0);
    __syncthreads();
    Xs[lk + 0][lr] = xv.x; Xs[lk + 1][lr] = xv.y; Xs[lk + 2][lr] = xv.z; Xs[lk + 3][lr] = xv.w;
    Wgs[lk + 0][lr] = gv.x; Wgs[lk + 1][lr] = gv.y; Wgs[lk + 2][lr] = gv.z; Wgs[lk + 3][lr] = gv.w;
    Wus[lk + 0][lr] = uv.x; Wus[lk + 1][lr] = uv.y; Wus[lk + 2][lr] = uv.z; Wus[lk + 3][lr] = uv.w;
    __syncthreads();
#pragma unroll
    for (int k = 0; k < 16; ++k) {
      float4 av = *(const float4*)&Xs[k][tx << 2];
      float4 g4 = *(const float4*)&Wgs[k][ty << 2];
      float4 u4 = *(const float4*)&Wus[k][ty << 2];
      const float aa[4] = {av.x, av.y, av.z, av.w};
      const float gg[4] = {g4.x, g4.y, g4.z, g4.w};
      const float uu[4] = {u4.x, u4.y, u4.z, u4.w};
#pragma unroll
      for (int i = 0; i < 4; ++i)
#pragma unroll
        for (int jj = 0; jj < 4; ++jj) {
          accg[i][jj] += aa[i] * gg[jj];
          accu[i][jj] += aa[i] * uu[jj];
        }
    }
  }
  const int nc = n0 + (ty << 2);
#pragma unroll
  for (int i = 0; i < 4; ++i) {
    const int row = m0 + (tx << 2) + i;
    ushort4 og, ou;
    {
      float z0 = accg[i][0] + bg[nc + 0], z1 = accg[i][1] + bg[nc + 1];
      float z2 = accg[i][2] + bg[nc + 2], z3 = accg[i][3] + bg[nc + 3];
      og.x = f2bf(1.0f / (1.0f + __expf(-z0)));
      og.y = f2bf(1.0f / (1.0f + __expf(-z1)));
      og.z = f2bf(1.0f / (1.0f + __expf(-z2)));
      og.w = f2bf(1.0f / (1.0f + __expf(-z3)));
    }
    ou.x = f2bf(accu[i][0]); ou.y = f2bf(accu[i][1]);
    ou.z = f2bf(accu[i][2]); ou.w = f2bf(accu[i][3]);
    *(ushort4*)&G[(size_t)row * D + nc] = og;
    *(ushort4*)&U[(size_t)row * D + nc] = ou;
  }
}

// ---------------- Scan: 256 co-resident WGs, 4 state columns each ----------------
// slice[t][g][b][jj]: 128 B per (t,g) -> no cross-WG line sharing on the racing path.
// Flags: per-WG, padded to 64 B. Readers poll all 256 flags (no contended RMW).
__global__ __launch_bounds__(256) void k_scan(
    const float* __restrict__ A, const float* __restrict__ inp,
    const uint16_t* __restrict__ gate, const uint16_t* __restrict__ u,
    float* __restrict__ slice, int* flags) {
  __shared__ float Ss[8 * 1032];  // [b][1024 + 8 pad]
  const int g = blockIdx.x;
  const int tid = threadIdx.x;
  const int w = tid >> 6;    // wave 0..3 -> column j = 4g+w
  const int l = tid & 63;
  const int j = (g << 2) + w;
  // Register-cache this column's A row chunk: A[j][16l .. 16l+15], loaded once.
  float Areg[16];
#pragma unroll
  for (int q = 0; q < 4; ++q) {
    float4 a4 = *(const float4*)&A[(size_t)j * D + (l << 4) + (q << 2)];
    Areg[q * 4 + 0] = a4.x; Areg[q * 4 + 1] = a4.y;
    Areg[q * 4 + 2] = a4.z; Areg[q * 4 + 3] = a4.w;
  }
  for (int t = 0; t < SEQ; ++t) {
    float dot[8] = {0.f, 0.f, 0.f, 0.f, 0.f, 0.f, 0.f, 0.f};
    if (t > 0) {
      if (w == 0) {  // wave 0 polls all 256 flags (4 per lane)
        while (true) {
          int f0 = __hip_atomic_load(&flags[(l      ) * 16], __ATOMIC_RELAXED, __HIP_MEMORY_SCOPE_AGENT);
          int f1 = __hip_atomic_load(&flags[(l +  64) * 16], __ATOMIC_RELAXED, __HIP_MEMORY_SCOPE_AGENT);
          int f2 = __hip_atomic_load(&flags[(l + 128) * 16], __ATOMIC_RELAXED, __HIP_MEMORY_SCOPE_AGENT);
          int f3 = __hip_atomic_load(&flags[(l + 192) * 16], __ATOMIC_RELAXED, __HIP_MEMORY_SCOPE_AGENT);
          bool ok = (f0 >= t) & (f1 >= t) & (f2 >= t) & (f3 >= t);
          if (__all(ok)) break;
          __builtin_amdgcn_s_sleep(1);
        }
        __threadfence();  // acquire: invalidate stale caches before state reads
      }
      __syncthreads();
      // Stage s_{t-1} (32 KB, contiguous) into LDS as Ss[b][i], i = 4*g'+jj.
      const float* src = slice + (size_t)(t - 1) * 8192;
#pragma unroll
      for (int q = 0; q < 8; ++q) {
        const int f4i = tid + (q << 8);              // float4 index 0..2047
        float4 v = *(const float4*)(src + ((size_t)f4i << 2));
        const int b = f4i & 7;
        const int gg2 = f4i >> 3;
        *(float4*)&Ss[b * 1032 + (gg2 << 2)] = v;
      }
      __syncthreads();
      // Partial dots: lane l covers i in [16l, 16l+16) for all 8 batches.
#pragma unroll
      for (int b = 0; b < 8; ++b) {
        const float* sb = &Ss[b * 1032 + (l << 4)];
        float d0 = 0.f;
#pragma unroll
        for (int q = 0; q < 4; ++q) {
          float4 s4 = *(const float4*)(sb + (q << 2));
          d0 += s4.x * Areg[q * 4 + 0];
          d0 += s4.y * Areg[q * 4 + 1];
          d0 += s4.z * Areg[q * 4 + 2];
          d0 += s4.w * Areg[q * 4 + 3];
        }
        dot[b] = d0;
      }
    }
    // Wave-wide reduction (64 lanes) of the 8 per-batch partials.
#pragma unroll
    for (int off = 1; off < 64; off <<= 1) {
#pragma unroll
      for (int b = 0; b < 8; ++b) dot[b] += __shfl_xor(dot[b], off, 64);
    }
    if (l == 0) {
#pragma unroll 1
      for (int b = 0; b < 8; ++b) {
        const size_t ridx = ((size_t)(b << 12) + t) * D + j;  // (b*4096+t)*1024+j
        const float pre = dot[b] + bf2f(u[ridx]);
        const float gt = bf2f(gate[ridx]);
        const float sv = tanhf(pre);
        const float val = gt * sv + (1.f - gt) * inp[ridx];
        slice[((size_t)t << 13) + (g << 5) + (b << 2) + w] = val;
      }
    }
    __syncthreads();  // all 4 waves' stores drained (waitcnt before s_barrier)
    if (tid == 0) {
      __threadfence();  // release: make slice stores device-visible
      __hip_atomic_store(&flags[g * 16], t + 1, __ATOMIC_RELAXED, __HIP_MEMORY_SCOPE_AGENT);
    }
  }
}

// ---------------- GEMM 3: out = states @ W_out^T + b_out (reads slice layout) ----------------
__global__ __launch_bounds__(256) void k_gemm_out(
    const float* __restrict__ S, const float* __restrict__ W,
    const float* __restrict__ bias, float* __restrict__ Y) {
  __shared__ float Xs[16][68];
  __shared__ float Ws[16][68];
  const int tid = threadIdx.x;
  const int m0 = blockIdx.y << 6, n0 = blockIdx.x << 6;
  const int tx = tid & 15, ty = tid >> 4;
  const int lr = tid >> 2, lk = (tid & 3) << 2;
  const int bb_ = m0 >> 12;          // batch (m-block never crosses batch: 4096 % 64 == 0)
  const int t0 = (m0 & 4095) + lr;   // time index of this loader row
  float acc[4][4] = {};
  const float* wp = W + (size_t)(n0 + lr) * D + lk;
  for (int k0 = 0; k0 < D; k0 += 16) {
    const int k = k0 + lk;
    // states(r=b*4096+t, k) lives at slice[t*8192 + (k>>2)*32 + b*4 + (k&3)]
    float4 xv = *(const float4*)(S + ((size_t)t0 << 13) + ((size_t)(k >> 2) << 5) + (bb_ << 2));
    float4 wv = *(const float4*)(wp + k0);
    __syncthreads();
    Xs[lk + 0][lr] = xv.x; Xs[lk + 1][lr] = xv.y; Xs[lk + 2][lr] = xv.z; Xs[lk + 3][lr] = xv.w;
    Ws[lk + 0][lr] = wv.x; Ws[lk + 1][lr] = wv.y; Ws[lk + 2][lr] = wv.z; Ws[lk + 3][lr] = wv.w;
    __syncthreads();
#pragma unroll
    for (int kk = 0; kk < 16; ++kk) {
      float4 av = *(const float4*)&Xs[kk][tx << 2];
      float4 bv = *(const float4*)&Ws[kk][ty << 2];
      const float aa[4] = {av.x, av.y, av.z, av.w};
      const float bb[4] = {bv.x, bv.y, bv.z, bv.w};
#pragma unroll
      for (int i = 0; i < 4; ++i)
#pragma unroll
        for (int jj = 0; jj < 4; ++jj) acc[i][jj] += aa[i] * bb[jj];
    }
  }
  const int nc = n0 + (ty << 2);
#pragma unroll
  for (int i = 0; i < 4; ++i) {
    const int row = m0 + (tx << 2) + i;
    float4 o;
    o.x = acc[i][0] + bias[nc + 0];
    o.y = acc[i][1] + bias[nc + 1];
    o.z = acc[i][2] + bias[nc + 2];
    o.w = acc[i][3] + bias[nc + 3];
    *(float4*)&Y[(size_t)row * D + nc] = o;
  }
}

extern "C" void kernel_launch(void* const* d_in, const int* in_sizes, int n_in,
                              void* d_out, int out_size, void* d_ws, size_t ws_size,
                              hipStream_t stream) {
  const float* x      = (const float*)d_in[0];
  const float* A      = (const float*)d_in[1];
  const float* B      = (const float*)d_in[2];
  const float* W_in   = (const float*)d_in[3];
  const float* b_in   = (const float*)d_in[4];
  const float* W_gate = (const float*)d_in[5];
  const float* b_gate = (const float*)d_in[6];
  const float* W_out  = (const float*)d_in[7];
  const float* b_out  = (const float*)d_in[8];
  float* out = (float*)d_out;
  char* ws = (char*)d_ws;

  int* flags      = (int*)ws;
  uint16_t* gate  = (uint16_t*)(ws + FLAGS_BYTES);
  uint16_t* u     = (uint16_t*)(ws + FLAGS_BYTES + GATE_BYTES);
  float* slice    = (float*)(ws + FLAGS_BYTES + GATE_BYTES + U_BYTES);

  hipMemsetAsync(flags, 0, FLAGS_BYTES, stream);

  dim3 gg(D / 64, NROWS / 64);
  // inp parked in d_out (fp32) until k_gemm_out overwrites it.
  k_gemm_in<<<gg, 256, 0, stream>>>(x, W_in, b_in, out);
  k_gemm_gate_u<<<gg, 256, 0, stream>>>(out, W_gate, b_gate, B, gate, u);
  k_scan<<<256, 256, 0, stream>>>(A, out, gate, u, slice, flags);
  k_gemm_out<<<gg, 256, 0, stream>>>(slice, W_out, b_out, out);
}

// Round 2
// 18001.799 us; speedup vs baseline: 4.9481x; 4.9481x over previous
//
#include <hip/hip_runtime.h>
#include <stdint.h>

// MambaBlock: DIM=1024, BATCH=8, SEQ=4096.
//   inp  = x @ W_in^T + b_in                  (fp32, stored in d_out temporarily)
//   gate = sigmoid(inp @ W_gate^T + b_gate)   (bf16 in ws)
//   u    = inp @ B^T                          (bf16 in ws)
//   scan: s_t = g*tanh(s_{t-1}@A^T + u_t) + (1-g)*inp_t   (fp32, LLC atomic exchange)
//   out  = states @ W_out^T + b_out           (fp32 -> d_out)

#define D 1024
#define NBATCH 8
#define SEQ 4096
#define NROWS 32768  // NBATCH*SEQ

static constexpr size_t FLAGS_BYTES = 16384;                     // 256 flags padded to 64B
static constexpr size_t GATE_BYTES  = (size_t)NROWS * D * 2;     // 64 MiB bf16
static constexpr size_t U_BYTES     = (size_t)NROWS * D * 2;     // 64 MiB bf16
// slice: [SEQ][256 g][8 b][4 jj] fp32 = 128 MiB. Exchange path is agent-scope
// atomics only (write-through to LLC; loads bypass L1/L2) -> NO fences needed:
// flag store is ordered behind data stores by the vmcnt(0) drain at s_barrier.

__device__ __forceinline__ float bf2f(uint16_t h) {
  uint32_t u = ((uint32_t)h) << 16;
  return __builtin_bit_cast(float, u);
}
__device__ __forceinline__ uint16_t f2bf(float f) {
  uint32_t u = __builtin_bit_cast(uint32_t, f);
  u = u + 0x7fffu + ((u >> 16) & 1u);   // RNE
  return (uint16_t)(u >> 16);
}

// ---------------- GEMM 1: inp = x @ W_in^T + b_in (fp32 out) ----------------
__global__ __launch_bounds__(256) void k_gemm_in(
    const float* __restrict__ X, const float* __restrict__ W,
    const float* __restrict__ bias, float* __restrict__ Y) {
  __shared__ float Xs[16][68];
  __shared__ float Ws[16][68];
  const int tid = threadIdx.x;
  const int m0 = blockIdx.y << 6, n0 = blockIdx.x << 6;
  const int tx = tid & 15, ty = tid >> 4;
  const int lr = tid >> 2, lk = (tid & 3) << 2;
  float acc[4][4] = {};
  const float* xp = X + (size_t)(m0 + lr) * D + lk;
  const float* wp = W + (size_t)(n0 + lr) * D + lk;
  for (int k0 = 0; k0 < D; k0 += 16) {
    float4 xv = *(const float4*)(xp + k0);
    float4 wv = *(const float4*)(wp + k0);
    __syncthreads();
    Xs[lk + 0][lr] = xv.x; Xs[lk + 1][lr] = xv.y; Xs[lk + 2][lr] = xv.z; Xs[lk + 3][lr] = xv.w;
    Ws[lk + 0][lr] = wv.x; Ws[lk + 1][lr] = wv.y; Ws[lk + 2][lr] = wv.z; Ws[lk + 3][lr] = wv.w;
    __syncthreads();
#pragma unroll
    for (int k = 0; k < 16; ++k) {
      float4 av = *(const float4*)&Xs[k][tx << 2];
      float4 bv = *(const float4*)&Ws[k][ty << 2];
      const float aa[4] = {av.x, av.y, av.z, av.w};
      const float bb[4] = {bv.x, bv.y, bv.z, bv.w};
#pragma unroll
      for (int i = 0; i < 4; ++i)
#pragma unroll
        for (int jj = 0; jj < 4; ++jj) acc[i][jj] += aa[i] * bb[jj];
    }
  }
  const int nc = n0 + (ty << 2);
#pragma unroll
  for (int i = 0; i < 4; ++i) {
    const int row = m0 + (tx << 2) + i;
    float4 o;
    o.x = acc[i][0] + bias[nc + 0];
    o.y = acc[i][1] + bias[nc + 1];
    o.z = acc[i][2] + bias[nc + 2];
    o.w = acc[i][3] + bias[nc + 3];
    *(float4*)&Y[(size_t)row * D + nc] = o;
  }
}

// ------- GEMM 2 (fused): gate = sigmoid(inp@Wg^T + bg), u = inp@B^T (bf16 out) -------
__global__ __launch_bounds__(256) void k_gemm_gate_u(
    const float* __restrict__ X, const float* __restrict__ Wg,
    const float* __restrict__ bg, const float* __restrict__ Bu,
    uint16_t* __restrict__ G, uint16_t* __restrict__ U) {
  __shared__ float Xs[16][68];
  __shared__ float Wgs[16][68];
  __shared__ float Wus[16][68];
  const int tid = threadIdx.x;
  const int m0 = blockIdx.y << 6, n0 = blockIdx.x << 6;
  const int tx = tid & 15, ty = tid >> 4;
  const int lr = tid >> 2, lk = (tid & 3) << 2;
  float accg[4][4] = {}, accu[4][4] = {};
  const float* xp = X + (size_t)(m0 + lr) * D + lk;
  const float* wgp = Wg + (size_t)(n0 + lr) * D + lk;
  const float* wup = Bu + (size_t)(n0 + lr) * D + lk;
  for (int k0 = 0; k0 < D; k0 += 16) {
    float4 xv = *(const float4*)(xp + k0);
    float4 gv = *(const float4*)(wgp + k0);
    float4 uv = *(const float4*)(wup + k0);
    __syncthreads();
    Xs[lk + 0][lr] = xv.x; Xs[lk + 1][lr] = xv.y; Xs[lk + 2][lr] = xv.z; Xs[lk + 3][lr] = xv.w;
    Wgs[lk + 0][lr] = gv.x; Wgs[lk + 1][lr] = gv.y; Wgs[lk + 2][lr] = gv.z; Wgs[lk + 3][lr] = gv.w;
    Wus[lk + 0][lr] = uv.x; Wus[lk + 1][lr] = uv.y; Wus[lk + 2][lr] = uv.z; Wus[lk + 3][lr] = uv.w;
    __syncthreads();
#pragma unroll
    for (int k = 0; k < 16; ++k) {
      float4 av = *(const float4*)&Xs[k][tx << 2];
      float4 g4 = *(const float4*)&Wgs[k][ty << 2];
      float4 u4 = *(const float4*)&Wus[k][ty << 2];
      const float aa[4] = {av.x, av.y, av.z, av.w};
      const float gg[4] = {g4.x, g4.y, g4.z, g4.w};
      const float uu[4] = {u4.x, u4.y, u4.z, u4.w};
#pragma unroll
      for (int i = 0; i < 4; ++i)
#pragma unroll
        for (int jj = 0; jj < 4; ++jj) {
          accg[i][jj] += aa[i] * gg[jj];
          accu[i][jj] += aa[i] * uu[jj];
        }
    }
  }
  const int nc = n0 + (ty << 2);
#pragma unroll
  for (int i = 0; i < 4; ++i) {
    const int row = m0 + (tx << 2) + i;
    ushort4 og, ou;
    {
      float z0 = accg[i][0] + bg[nc + 0], z1 = accg[i][1] + bg[nc + 1];
      float z2 = accg[i][2] + bg[nc + 2], z3 = accg[i][3] + bg[nc + 3];
      og.x = f2bf(1.0f / (1.0f + __expf(-z0)));
      og.y = f2bf(1.0f / (1.0f + __expf(-z1)));
      og.z = f2bf(1.0f / (1.0f + __expf(-z2)));
      og.w = f2bf(1.0f / (1.0f + __expf(-z3)));
    }
    ou.x = f2bf(accu[i][0]); ou.y = f2bf(accu[i][1]);
    ou.z = f2bf(accu[i][2]); ou.w = f2bf(accu[i][3]);
    *(ushort4*)&G[(size_t)row * D + nc] = og;
    *(ushort4*)&U[(size_t)row * D + nc] = ou;
  }
}

// ---------------- Scan: 256 co-resident WGs, 4 state columns each ----------------
// Fence-free exchange: data stores + flag store + staging loads are all
// agent-scope relaxed atomics (LLC is the single serialization point).
// L1/L2 are never invalidated -> gate/u/inp stay cached.
#define SB 1028  // LDS b-stride in floats (16B-aligned, breaks pow2)
__global__ __launch_bounds__(256) void k_scan(
    const float* __restrict__ A, const float* __restrict__ inp,
    const uint16_t* __restrict__ gate, const uint16_t* __restrict__ u,
    float* __restrict__ slice, int* flags) {
  __shared__ float Ss[8 * SB];
  const int g = blockIdx.x;
  const int tid = threadIdx.x;
  const int w = tid >> 6;    // wave 0..3 -> column j = 4g+w
  const int l = tid & 63;
  const int j = (g << 2) + w;
  // Lane l owns i-chunks {4l+256q}: A frags coalesced, LDS reads conflict-free.
  float4 Areg[4];
#pragma unroll
  for (int q = 0; q < 4; ++q)
    Areg[q] = *(const float4*)&A[(size_t)j * D + (q << 8) + (l << 2)];

  const unsigned long long* slice8 = (const unsigned long long*)slice;

  for (int t = 0; t < SEQ; ++t) {
    // ---- prefetch gate/u/inp for this step (lanes 0..7, batch = lane) ----
    float pg = 0.f, pu = 0.f, pi = 0.f;
    if (l < 8) {
      const size_t ridx = ((size_t)(l << 12) + t) * D + j;  // (b*4096+t)*1024+j
      pg = bf2f(gate[ridx]);
      pu = bf2f(u[ridx]);
      pi = inp[ridx];
    }
    asm volatile("" : "+v"(pg), "+v"(pu), "+v"(pi));  // force issue before poll

    float dot[8] = {0.f, 0.f, 0.f, 0.f, 0.f, 0.f, 0.f, 0.f};
    if (t > 0) {
      if (w == 0) {  // wave 0 polls all 256 flags (4 per lane), relaxed agent
        while (true) {
          int f0 = __hip_atomic_load(&flags[(l      ) << 4], __ATOMIC_RELAXED, __HIP_MEMORY_SCOPE_AGENT);
          int f1 = __hip_atomic_load(&flags[(l +  64) << 4], __ATOMIC_RELAXED, __HIP_MEMORY_SCOPE_AGENT);
          int f2 = __hip_atomic_load(&flags[(l + 128) << 4], __ATOMIC_RELAXED, __HIP_MEMORY_SCOPE_AGENT);
          int f3 = __hip_atomic_load(&flags[(l + 192) << 4], __ATOMIC_RELAXED, __HIP_MEMORY_SCOPE_AGENT);
          bool ok = (f0 >= t) & (f1 >= t) & (f2 >= t) & (f3 >= t);
          if (__all(ok)) break;
          __builtin_amdgcn_s_sleep(1);
        }
      }
      __syncthreads();
      // Stage s_{t-1}: 4096 8B granules via LLC-direct atomic loads (16/thread,
      // all issued before first use -> pipelined).
      const unsigned long long* src8 = slice8 + ((size_t)(t - 1) << 12);
      unsigned long long vv[16];
#pragma unroll
      for (int q = 0; q < 16; ++q)
        vv[q] = __hip_atomic_load(&src8[tid + (q << 8)], __ATOMIC_RELAXED, __HIP_MEMORY_SCOPE_AGENT);
#pragma unroll
      for (int q = 0; q < 16; ++q) {
        const int e = tid + (q << 8);           // granule: floats [2e, 2e+1]
        const int b = (e >> 1) & 7;
        const int gg2 = e >> 4;                 // producer g
        const int m = (e & 1) << 1;             // jj pair offset 0 or 2
        *(unsigned long long*)&Ss[b * SB + (gg2 << 2) + m] = vv[q];
      }
      __syncthreads();
      // Conflict-free dot: uniform base + 4l lane offset.
#pragma unroll
      for (int b = 0; b < 8; ++b) {
        float d0 = 0.f;
#pragma unroll
        for (int q = 0; q < 4; ++q) {
          float4 s4 = *(const float4*)&Ss[b * SB + (q << 8) + (l << 2)];
          d0 += s4.x * Areg[q].x + s4.y * Areg[q].y + s4.z * Areg[q].z + s4.w * Areg[q].w;
        }
        dot[b] = d0;
      }
      __syncthreads();  // Ss consumed; safe to overwrite next iter
    }
    // Butterfly: every lane ends with all 8 full sums.
#pragma unroll
    for (int off = 1; off < 64; off <<= 1) {
#pragma unroll
      for (int b = 0; b < 8; ++b) dot[b] += __shfl_xor(dot[b], off, 64);
    }
    if (l < 8) {
      float dsel = dot[0];
#pragma unroll
      for (int b = 1; b < 8; ++b) dsel = (l == b) ? dot[b] : dsel;  // cndmask chain
      const float pre = dsel + pu;
      const float sv = tanhf(pre);
      const float val = pg * sv + (1.f - pg) * pi;
      // data store: agent atomic (write-through to LLC)
      __hip_atomic_store((uint32_t*)&slice[((size_t)t << 13) + (g << 5) + (l << 2) + w],
                         __builtin_bit_cast(uint32_t, val),
                         __ATOMIC_RELAXED, __HIP_MEMORY_SCOPE_AGENT);
    }
    __syncthreads();  // each wave drains vmcnt(0) before barrier -> data at LLC
    if (tid == 0)
      __hip_atomic_store(&flags[g << 4], t + 1, __ATOMIC_RELAXED, __HIP_MEMORY_SCOPE_AGENT);
  }
}

// ---------------- GEMM 3: out = states @ W_out^T + b_out (reads slice layout) ----------------
__global__ __launch_bounds__(256) void k_gemm_out(
    const float* __restrict__ S, const float* __restrict__ W,
    const float* __restrict__ bias, float* __restrict__ Y) {
  __shared__ float Xs[16][68];
  __shared__ float Ws[16][68];
  const int tid = threadIdx.x;
  const int m0 = blockIdx.y << 6, n0 = blockIdx.x << 6;
  const int tx = tid & 15, ty = tid >> 4;
  const int lr = tid >> 2, lk = (tid & 3) << 2;
  const int bb_ = m0 >> 12;          // batch (m-block never crosses batch: 4096 % 64 == 0)
  const int t0 = (m0 & 4095) + lr;   // time index of this loader row
  float acc[4][4] = {};
  const float* wp = W + (size_t)(n0 + lr) * D + lk;
  for (int k0 = 0; k0 < D; k0 += 16) {
    const int k = k0 + lk;
    // states(r=b*4096+t, k) lives at slice[t*8192 + (k>>2)*32 + b*4 + (k&3)]
    float4 xv = *(const float4*)(S + ((size_t)t0 << 13) + ((size_t)(k >> 2) << 5) + (bb_ << 2));
    float4 wv = *(const float4*)(wp + k0);
    __syncthreads();
    Xs[lk + 0][lr] = xv.x; Xs[lk + 1][lr] = xv.y; Xs[lk + 2][lr] = xv.z; Xs[lk + 3][lr] = xv.w;
    Ws[lk + 0][lr] = wv.x; Ws[lk + 1][lr] = wv.y; Ws[lk + 2][lr] = wv.z; Ws[lk + 3][lr] = wv.w;
    __syncthreads();
#pragma unroll
    for (int kk = 0; kk < 16; ++kk) {
      float4 av = *(const float4*)&Xs[kk][tx << 2];
      float4 bv = *(const float4*)&Ws[kk][ty << 2];
      const float aa[4] = {av.x, av.y, av.z, av.w};
      const float bb[4] = {bv.x, bv.y, bv.z, bv.w};
#pragma unroll
      for (int i = 0; i < 4; ++i)
#pragma unroll
        for (int jj = 0; jj < 4; ++jj) acc[i][jj] += aa[i] * bb[jj];
    }
  }
  const int nc = n0 + (ty << 2);
#pragma unroll
  for (int i = 0; i < 4; ++i) {
    const int row = m0 + (tx << 2) + i;
    float4 o;
    o.x = acc[i][0] + bias[nc + 0];
    o.y = acc[i][1] + bias[nc + 1];
    o.z = acc[i][2] + bias[nc + 2];
    o.w = acc[i][3] + bias[nc + 3];
    *(float4*)&Y[(size_t)row * D + nc] = o;
  }
}

extern "C" void kernel_launch(void* const* d_in, const int* in_sizes, int n_in,
                              void* d_out, int out_size, void* d_ws, size_t ws_size,
                              hipStream_t stream) {
  const float* x      = (const float*)d_in[0];
  const float* A      = (const float*)d_in[1];
  const float* B      = (const float*)d_in[2];
  const float* W_in   = (const float*)d_in[3];
  const float* b_in   = (const float*)d_in[4];
  const float* W_gate = (const float*)d_in[5];
  const float* b_gate = (const float*)d_in[6];
  const float* W_out  = (const float*)d_in[7];
  const float* b_out  = (const float*)d_in[8];
  float* out = (float*)d_out;
  char* ws = (char*)d_ws;

  int* flags      = (int*)ws;
  uint16_t* gate  = (uint16_t*)(ws + FLAGS_BYTES);
  uint16_t* u     = (uint16_t*)(ws + FLAGS_BYTES + GATE_BYTES);
  float* slice    = (float*)(ws + FLAGS_BYTES + GATE_BYTES + U_BYTES);

  hipMemsetAsync(flags, 0, FLAGS_BYTES, stream);

  dim3 gg(D / 64, NROWS / 64);
  // inp parked in d_out (fp32) until k_gemm_out overwrites it.
  k_gemm_in<<<gg, 256, 0, stream>>>(x, W_in, b_in, out);
  k_gemm_gate_u<<<gg, 256, 0, stream>>>(out, W_gate, b_gate, B, gate, u);
  k_scan<<<256, 256, 0, stream>>>(A, out, gate, u, slice, flags);
  k_gemm_out<<<gg, 256, 0, stream>>>(slice, W_out, b_out, out);
}